// Round 1
// baseline (510.807 us; speedup 1.0000x reference)
//
#include <hip/hip_runtime.h>
#include <hip/hip_bf16.h>

typedef __bf16 bf16;
typedef __bf16 bf16x8 __attribute__((ext_vector_type(8)));
typedef float f32x4 __attribute__((ext_vector_type(4)));

#define MFMA16(a, b, c) __builtin_amdgcn_mfma_f32_16x16x32_bf16((a), (b), (c), 0, 0, 0)

constexpr int EMBED = 1024;
constexpr int HEADS = 16;
constexpr int HD = 64;
constexpr int SEQ = 2048;
constexpr int NB = 4;
constexpr int LDSP = 72;  // padded LDS leading dim (bf16 elems), keeps 16B alignment

// ---------------- Wo fp32 -> bf16 ----------------
__global__ __launch_bounds__(256) void convert_wo(const float* __restrict__ Wo,
                                                  bf16* __restrict__ Wob) {
    int gid = blockIdx.x * 256 + threadIdx.x;
    int base = gid * 8;
    float4 a = *(const float4*)(Wo + base);
    float4 b = *(const float4*)(Wo + base + 4);
    bf16x8 o;
    o[0] = (bf16)a.x; o[1] = (bf16)a.y; o[2] = (bf16)a.z; o[3] = (bf16)a.w;
    o[4] = (bf16)b.x; o[5] = (bf16)b.y; o[6] = (bf16)b.z; o[7] = (bf16)b.w;
    *(bf16x8*)(Wob + base) = o;
}

// ---------------- QKV per-head projections ----------------
// Treats each tensor as a [131072, 64] x [64, 64]^T GEMM (rows = (n,l,h) flat).
// Writes Qp/Kp as [n,h,l,d] bf16; writes V transposed as [n,h,d,l] bf16 so the
// flash kernel's V B-fragments are contiguous ds_read_b128.
__global__ __launch_bounds__(256) void proj_kernel(
    const float* __restrict__ Vx, const float* __restrict__ Kx, const float* __restrict__ Qx,
    const float* __restrict__ Wv, const float* __restrict__ Wk, const float* __restrict__ Wq,
    bf16* __restrict__ Vp, bf16* __restrict__ Kp, bf16* __restrict__ Qp) {
    __shared__ __align__(16) bf16 sW[3][64 * LDSP];
    __shared__ __align__(16) bf16 sX[64 * LDSP];
    int t = threadIdx.x;
    // stage all three weight matrices once (W[e][d] rows = B-operand layout)
    for (int i = t; i < 4096; i += 256) {
        int e = i >> 6, d = i & 63;
        sW[0][e * LDSP + d] = (bf16)Wq[i];
        sW[1][e * LDSP + d] = (bf16)Wk[i];
        sW[2][e * LDSP + d] = (bf16)Wv[i];
    }
    int rowbase = blockIdx.x * 64;
    int lane = t & 63, wq = t >> 6;
    int m = lane & 15, q8 = lane >> 4;
    const float* Xs[3] = {Qx, Kx, Vx};

    for (int ts = 0; ts < 3; ts++) {
        __syncthreads();  // prior MFMAs done with sX (and first pass: nothing)
        const float* X = Xs[ts] + (size_t)rowbase * 64;
        for (int i = t; i < 1024; i += 256) {  // 64 rows x 16 float4
            int r = i >> 4, v = i & 15;
            float4 x4 = *(const float4*)(X + r * 64 + v * 4);
            bf16* dst = &sX[r * LDSP + v * 4];
            dst[0] = (bf16)x4.x; dst[1] = (bf16)x4.y; dst[2] = (bf16)x4.z; dst[3] = (bf16)x4.w;
        }
        __syncthreads();
        f32x4 z = {0.f, 0.f, 0.f, 0.f};
        f32x4 acc[4] = {z, z, z, z};
        for (int c = 0; c < 2; c++) {
            bf16x8 a = *(const bf16x8*)&sX[(wq * 16 + m) * LDSP + c * 32 + q8 * 8];
            for (int nt = 0; nt < 4; nt++) {
                bf16x8 b = *(const bf16x8*)&sW[ts][(nt * 16 + m) * LDSP + c * 32 + q8 * 8];
                acc[nt] = MFMA16(a, b, acc[nt]);
            }
        }
        // epilogue: C/D layout col=lane&15, row=(lane>>4)*4+reg
        for (int nt = 0; nt < 4; nt++) {
            int e = nt * 16 + m;
            for (int jr = 0; jr < 4; jr++) {
                int R = rowbase + wq * 16 + q8 * 4 + jr;
                int h = R & 15, l = (R >> 4) & 2047, n = R >> 15;
                float val = acc[nt][jr];
                if (ts == 0) {
                    Qp[((size_t)(n * HEADS + h) * SEQ + l) * HD + e] = (bf16)val;
                } else if (ts == 1) {
                    Kp[((size_t)(n * HEADS + h) * SEQ + l) * HD + e] = (bf16)val;
                } else {
                    Vp[((size_t)(n * HEADS + h) * HD + e) * SEQ + l] = (bf16)val;
                }
            }
        }
    }
}

// ---------------- flash attention ----------------
// One workgroup = (n, h, 64 q-rows); 4 waves x 16 q-rows each.
// K tiles of 64 over SEQ; online softmax; P via LDS round-trip (m120 pattern).
__global__ __launch_bounds__(256) void flash_kernel(
    const bf16* __restrict__ Qp, const bf16* __restrict__ Kp, const bf16* __restrict__ Vp,
    bf16* __restrict__ O) {
    int qt = blockIdx.x, h = blockIdx.y, n = blockIdx.z;
    int t = threadIdx.x, lane = t & 63, wq = t >> 6;
    int m = lane & 15, q8 = lane >> 4;
    __shared__ __align__(16) bf16 sK[64 * LDSP];
    __shared__ __align__(16) bf16 sV[64 * LDSP];  // transposed: sV[e][l]
    __shared__ __align__(16) bf16 sP[4][16 * LDSP];
    size_t nh = (size_t)(n * HEADS + h);
    const bf16* Qb = Qp + (nh * SEQ + (size_t)qt * 64 + wq * 16) * HD;
    const bf16* Kb = Kp + nh * SEQ * HD;
    const bf16* Vb = Vp + nh * HD * SEQ;

    bf16x8 qfrag[2];
    qfrag[0] = *(const bf16x8*)(Qb + m * HD + q8 * 8);
    qfrag[1] = *(const bf16x8*)(Qb + m * HD + 32 + q8 * 8);

    f32x4 z = {0.f, 0.f, 0.f, 0.f};
    f32x4 accO[4] = {z, z, z, z};
    float mrow[4], lrow[4];
    for (int j = 0; j < 4; j++) { mrow[j] = -1e30f; lrow[j] = 0.f; }
    const float scale = 0.03125f;  // 1/sqrt(EMBED)

    for (int kb = 0; kb < SEQ; kb += 64) {
        __syncthreads();  // previous PV done with sV/sP
        for (int i = t; i < 512; i += 256) {
            int r = i >> 3, v = i & 7;
            *(bf16x8*)&sK[r * LDSP + v * 8] = *(const bf16x8*)(Kb + (size_t)(kb + r) * HD + v * 8);
            *(bf16x8*)&sV[r * LDSP + v * 8] = *(const bf16x8*)(Vb + (size_t)r * SEQ + kb + v * 8);
        }
        __syncthreads();
        // S = Q K^T: 16 rows x 64 cols per wave
        f32x4 s[4] = {z, z, z, z};
        for (int c = 0; c < 2; c++) {
            for (int kt = 0; kt < 4; kt++) {
                bf16x8 b = *(const bf16x8*)&sK[(kt * 16 + m) * LDSP + c * 32 + q8 * 8];
                s[kt] = MFMA16(qfrag[c], b, s[kt]);
            }
        }
        for (int kt = 0; kt < 4; kt++)
            for (int j = 0; j < 4; j++) s[kt][j] *= scale;
        // online softmax; row j lives in the 16-lane group sharing q8
        float alpha[4];
        for (int j = 0; j < 4; j++) {
            float tmax = fmaxf(fmaxf(s[0][j], s[1][j]), fmaxf(s[2][j], s[3][j]));
            for (int msk = 1; msk < 16; msk <<= 1) tmax = fmaxf(tmax, __shfl_xor(tmax, msk));
            float newm = fmaxf(mrow[j], tmax);
            alpha[j] = expf(mrow[j] - newm);
            mrow[j] = newm;
            float tsum = 0.f;
            for (int kt = 0; kt < 4; kt++) {
                float p = expf(s[kt][j] - newm);
                s[kt][j] = p;
                tsum += p;
            }
            for (int msk = 1; msk < 16; msk <<= 1) tsum += __shfl_xor(tsum, msk);
            lrow[j] = lrow[j] * alpha[j] + tsum;
        }
        // P -> LDS (C-layout write, A-layout read)
        for (int kt = 0; kt < 4; kt++)
            for (int j = 0; j < 4; j++)
                sP[wq][(q8 * 4 + j) * LDSP + kt * 16 + m] = (bf16)s[kt][j];
        __syncthreads();  // P visible
        for (int nt = 0; nt < 4; nt++)
            for (int j = 0; j < 4; j++) accO[nt][j] *= alpha[j];
        // O += P V
        for (int c = 0; c < 2; c++) {
            bf16x8 a = *(const bf16x8*)&sP[wq][m * LDSP + c * 32 + q8 * 8];
            for (int nt = 0; nt < 4; nt++) {
                bf16x8 b = *(const bf16x8*)&sV[(nt * 16 + m) * LDSP + c * 32 + q8 * 8];
                accO[nt] = MFMA16(a, b, accO[nt]);
            }
        }
    }
    // epilogue: O row-normalize, store bf16 [n*SEQ+q][EMBED] at head's column slice
    for (int j = 0; j < 4; j++) {
        float inv = 1.f / lrow[j];
        int q = qt * 64 + wq * 16 + q8 * 4 + j;
        size_t rowoff = ((size_t)n * SEQ + q) * EMBED + h * HD;
        for (int nt = 0; nt < 4; nt++) {
            O[rowoff + nt * 16 + m] = (bf16)(accO[nt][j] * inv);
        }
    }
}

// ---------------- output projection: out = O @ Wo^T + bo ----------------
__global__ __launch_bounds__(256) void outproj_kernel(
    const bf16* __restrict__ O, const bf16* __restrict__ Wob,
    const float* __restrict__ bo, float* __restrict__ out) {
    int qt = blockIdx.x, et = blockIdx.y;
    int t = threadIdx.x, lane = t & 63, wq = t >> 6;
    int m = lane & 15, q8 = lane >> 4;
    __shared__ __align__(16) bf16 sA[64 * LDSP];
    __shared__ __align__(16) bf16 sB[64 * LDSP];
    f32x4 z = {0.f, 0.f, 0.f, 0.f};
    f32x4 acc[4] = {z, z, z, z};
    const bf16* Ab = O + (size_t)qt * 64 * EMBED;
    const bf16* Bb = Wob + (size_t)et * 64 * EMBED;
    for (int kk = 0; kk < EMBED; kk += 64) {
        __syncthreads();
        for (int i = t; i < 512; i += 256) {
            int r = i >> 3, v = i & 7;
            *(bf16x8*)&sA[r * LDSP + v * 8] = *(const bf16x8*)(Ab + (size_t)r * EMBED + kk + v * 8);
            *(bf16x8*)&sB[r * LDSP + v * 8] = *(const bf16x8*)(Bb + (size_t)r * EMBED + kk + v * 8);
        }
        __syncthreads();
        for (int c = 0; c < 2; c++) {
            bf16x8 a = *(const bf16x8*)&sA[(wq * 16 + m) * LDSP + c * 32 + q8 * 8];
            for (int nt = 0; nt < 4; nt++) {
                bf16x8 b = *(const bf16x8*)&sB[(nt * 16 + m) * LDSP + c * 32 + q8 * 8];
                acc[nt] = MFMA16(a, b, acc[nt]);
            }
        }
    }
    for (int nt = 0; nt < 4; nt++) {
        int col = et * 64 + nt * 16 + m;
        float bias = bo[col];
        for (int j = 0; j < 4; j++) {
            int q = qt * 64 + wq * 16 + q8 * 4 + j;
            out[(size_t)q * EMBED + col] = acc[nt][j] + bias;
        }
    }
}

extern "C" void kernel_launch(void* const* d_in, const int* in_sizes, int n_in,
                              void* d_out, int out_size, void* d_ws, size_t ws_size,
                              hipStream_t stream) {
    const float* values = (const float*)d_in[0];
    const float* keys   = (const float*)d_in[1];
    const float* query  = (const float*)d_in[2];
    const float* Wv     = (const float*)d_in[3];
    const float* Wk     = (const float*)d_in[4];
    const float* Wq     = (const float*)d_in[5];
    const float* Wo     = (const float*)d_in[6];
    const float* bo     = (const float*)d_in[7];
    float* out = (float*)d_out;

    char* ws = (char*)d_ws;
    // each of Qp/Kp/Vp/O is exactly 16 MiB of bf16; Wo_bf16 is 2 MiB
    bf16* Qp  = (bf16*)(ws);
    bf16* Kp  = (bf16*)(ws + (size_t)(16 << 20));
    bf16* Vp  = (bf16*)(ws + (size_t)(32 << 20));
    bf16* O   = (bf16*)(ws + (size_t)(48 << 20));
    bf16* Wob = (bf16*)(ws + (size_t)(64 << 20));

    hipLaunchKernelGGL(convert_wo, dim3(512), dim3(256), 0, stream, Wo, Wob);
    hipLaunchKernelGGL(proj_kernel, dim3(2048), dim3(256), 0, stream,
                       values, keys, query, Wv, Wk, Wq, Vp, Kp, Qp);
    hipLaunchKernelGGL(flash_kernel, dim3(32, HEADS, NB), dim3(256), 0, stream, Qp, Kp, Vp, O);
    hipLaunchKernelGGL(outproj_kernel, dim3(128, 16), dim3(256), 0, stream, O, Wob, bo, out);
}